// Round 1
// baseline (903.949 us; speedup 1.0000x reference)
//
#include <hip/hip_runtime.h>
#include <hip/hip_bf16.h>

typedef __attribute__((ext_vector_type(8))) short short8;
typedef __attribute__((ext_vector_type(4))) float f32x4;

#if __has_builtin(__builtin_amdgcn_exp2f)
#define EXP2F(x) __builtin_amdgcn_exp2f(x)
#else
#define EXP2F(x) exp2f(x)
#endif
#if __has_builtin(__builtin_amdgcn_rcpf)
#define RCPF(x) __builtin_amdgcn_rcpf(x)
#else
#define RCPF(x) (1.0f/(x))
#endif

#define SMEM_BYTES 132096

__device__ __forceinline__ unsigned short f2bf(float f) {
    union { float f; unsigned u; } v; v.f = f;
    unsigned r = v.u + 0x7FFFu + ((v.u >> 16) & 1u);
    return (unsigned short)(r >> 16);
}

__global__ void cvt_weights(const float* __restrict__ qw, const float* __restrict__ hw,
                            unsigned short* __restrict__ wq, unsigned short* __restrict__ wh) {
    int i = blockIdx.x * 256 + threadIdx.x;
    if (i < 576 * 192) wq[i] = f2bf(qw[i]);
    if (i < 192 * 192) wh[i] = f2bf(hw[i]);
}

// One block per 8x8 window: 256 threads = 4 waves.
// LDS (bytes):
//   xo_lds [64][200] bf16 @0      (x staged, later o)      25600
//   q_lds  [64][200] bf16 @25600                           25600
//   k_lds  [64][200] bf16 @51200                           25600
//   v_lds  vT [192][72] bf16 @76800                        27648
//   p_lds  [3][64][72] bf16 @104448                        27648  -> 132096 total
__global__ __launch_bounds__(256, 1) void wmha(
    const float* __restrict__ x, const float* __restrict__ qkv_b,
    const float* __restrict__ head_b, const unsigned short* __restrict__ wq,
    const unsigned short* __restrict__ wh, float* __restrict__ out)
{
    extern __shared__ char smem[];
    char* const xo_lds = smem;
    char* const q_lds  = smem + 25600;
    char* const k_lds  = smem + 51200;
    char* const v_lds  = smem + 76800;
    char* const p_lds  = smem + 104448;

    const int tid = threadIdx.x;
    const int ln  = tid & 15;          // lane&15
    const int hi4 = (tid >> 4) & 3;    // lane>>4 within wave
    const int wid = tid >> 6;          // wave id 0..3

    const int bid  = blockIdx.x;
    const int widx = (bid & 7) * 1152 + (bid >> 3);   // bijective XCD swizzle (9216 % 8 == 0)
    const int b  = widx / 2304;
    const int rr = widx % 2304;
    const int oy = rr / 48, ox = rr % 48;
    const int row0 = oy * 8, col0 = ox * 8;

    // ---- Phase 0: stage x window -> LDS bf16 [t][c] (stride 400 B) ----
    {
        const int tok = tid & 63;
        const int qd  = tid >> 6;
        const int y = tok >> 3, xx = tok & 7;
        const float* gp = x + ((size_t)(b * 192) * 384 + (row0 + y)) * 384 + (col0 + xx);
        char* wp = xo_lds + tok * 400 + qd * 96;
        #pragma unroll
        for (int kk = 0; kk < 12; ++kk) {
            const int c = qd * 48 + kk * 4;
            float f0 = gp[(size_t)(c + 0) * 147456];
            float f1 = gp[(size_t)(c + 1) * 147456];
            float f2 = gp[(size_t)(c + 2) * 147456];
            float f3 = gp[(size_t)(c + 3) * 147456];
            uint2 u;
            u.x = (unsigned)f2bf(f0) | ((unsigned)f2bf(f1) << 16);
            u.y = (unsigned)f2bf(f2) | ((unsigned)f2bf(f3) << 16);
            *(uint2*)(wp + kk * 8) = u;
        }
    }
    __syncthreads();

    // preload all x B-frags into registers (24 frags = whole window, 96 VGPR)
    short8 bx[4][6];
    #pragma unroll
    for (int nt = 0; nt < 4; ++nt)
        #pragma unroll
        for (int kt = 0; kt < 6; ++kt)
            bx[nt][kt] = *(const short8*)(xo_lds + (nt * 16 + ln) * 400 + kt * 64 + hi4 * 16);

    // ---- Phase 1: QKV projection. D[outch][t] = W[outch][c] * x[t][c] ----
    {
        const int OB = wid * 144;        // 9 m-tiles per wave
        for (int mt = 0; mt < 9; ++mt) {
            const int ob = OB + mt * 16;
            short8 af[6];
            #pragma unroll
            for (int kt = 0; kt < 6; ++kt)
                af[kt] = *(const short8*)(wq + (ob + ln) * 192 + kt * 32 + hi4 * 8);
            float bias[4];
            #pragma unroll
            for (int r = 0; r < 4; ++r) bias[r] = qkv_b[ob + hi4 * 4 + r];
            #pragma unroll
            for (int nt = 0; nt < 4; ++nt) {
                f32x4 acc = {0.f, 0.f, 0.f, 0.f};
                #pragma unroll
                for (int kt = 0; kt < 6; ++kt)
                    acc = __builtin_amdgcn_mfma_f32_16x16x32_bf16(af[kt], bx[nt][kt], acc, 0, 0, 0);
                const int t = nt * 16 + ln;
                const int oc0 = ob + hi4 * 4;   // 4 consecutive outch via regs
                if (ob < 192) {                  // q -> [t][d]
                    uint2 u;
                    u.x = (unsigned)f2bf(acc[0] + bias[0]) | ((unsigned)f2bf(acc[1] + bias[1]) << 16);
                    u.y = (unsigned)f2bf(acc[2] + bias[2]) | ((unsigned)f2bf(acc[3] + bias[3]) << 16);
                    *(uint2*)(q_lds + t * 400 + oc0 * 2) = u;
                } else if (ob < 384) {           // k -> [t][d]
                    uint2 u;
                    u.x = (unsigned)f2bf(acc[0] + bias[0]) | ((unsigned)f2bf(acc[1] + bias[1]) << 16);
                    u.y = (unsigned)f2bf(acc[2] + bias[2]) | ((unsigned)f2bf(acc[3] + bias[3]) << 16);
                    *(uint2*)(k_lds + t * 400 + (oc0 - 192) * 2) = u;
                } else {                         // v -> vT [d][t] (scatter)
                    #pragma unroll
                    for (int r = 0; r < 4; ++r)
                        *(unsigned short*)(v_lds + (oc0 - 384 + r) * 144 + t * 2) = f2bf(acc[r] + bias[r]);
                }
            }
        }
    }
    __syncthreads();

    const float SC2 = 0.25503417f;  // (1/sqrt(32)) * log2(e)

    for (int g = 0; g < 2; ++g) {
        // ---- scores + softmax for heads 3g..3g+2 -> p_lds ----
        #pragma unroll
        for (int uu = 0; uu < 3; ++uu) {
            const int u = wid + uu * 4;          // 0..11
            const int hl = u >> 2, it = u & 3;
            const int h = g * 3 + hl;
            const int i0 = it * 16;
            const short8 aq = *(const short8*)(q_lds + (i0 + ln) * 400 + h * 64 + hi4 * 16);
            f32x4 s[4];
            #pragma unroll
            for (int jt = 0; jt < 4; ++jt) {
                const short8 bk = *(const short8*)(k_lds + (jt * 16 + ln) * 400 + h * 64 + hi4 * 16);
                f32x4 z = {0.f, 0.f, 0.f, 0.f};
                s[jt] = __builtin_amdgcn_mfma_f32_16x16x32_bf16(aq, bk, z, 0, 0, 0);
            }
            #pragma unroll
            for (int r = 0; r < 4; ++r) {
                float m = fmaxf(fmaxf(s[0][r], s[1][r]), fmaxf(s[2][r], s[3][r]));
                m = fmaxf(m, __shfl_xor(m, 1));
                m = fmaxf(m, __shfl_xor(m, 2));
                m = fmaxf(m, __shfl_xor(m, 4));
                m = fmaxf(m, __shfl_xor(m, 8));
                float p0 = EXP2F((s[0][r] - m) * SC2);
                float p1 = EXP2F((s[1][r] - m) * SC2);
                float p2 = EXP2F((s[2][r] - m) * SC2);
                float p3 = EXP2F((s[3][r] - m) * SC2);
                float sum = p0 + p1 + p2 + p3;
                sum += __shfl_xor(sum, 1);
                sum += __shfl_xor(sum, 2);
                sum += __shfl_xor(sum, 4);
                sum += __shfl_xor(sum, 8);
                const float rinv = RCPF(sum);
                char* pr = p_lds + (hl * 64 + i0 + hi4 * 4 + r) * 144 + ln * 2;
                *(unsigned short*)(pr + 0)  = f2bf(p0 * rinv);
                *(unsigned short*)(pr + 32) = f2bf(p1 * rinv);
                *(unsigned short*)(pr + 64) = f2bf(p2 * rinv);
                *(unsigned short*)(pr + 96) = f2bf(p3 * rinv);
            }
        }
        __syncthreads();

        // ---- PV: O[i][d] = P[i][j] * v[j][d] -> o (in xo_lds) ----
        #pragma unroll
        for (int uu = 0; uu < 3; ++uu) {
            const int u = wid + uu * 4;
            const int hl = u >> 2, it = u & 3;
            const int h = g * 3 + hl;
            const int i0 = it * 16;
            short8 ap[2];
            #pragma unroll
            for (int kc = 0; kc < 2; ++kc)
                ap[kc] = *(const short8*)(p_lds + (hl * 64 + i0 + ln) * 144 + kc * 64 + hi4 * 16);
            #pragma unroll
            for (int dt = 0; dt < 2; ++dt) {
                f32x4 acc = {0.f, 0.f, 0.f, 0.f};
                #pragma unroll
                for (int kc = 0; kc < 2; ++kc) {
                    const short8 bv = *(const short8*)(v_lds + (h * 32 + dt * 16 + ln) * 144 + kc * 64 + hi4 * 16);
                    acc = __builtin_amdgcn_mfma_f32_16x16x32_bf16(ap[kc], bv, acc, 0, 0, 0);
                }
                #pragma unroll
                for (int r = 0; r < 4; ++r)
                    *(unsigned short*)(xo_lds + (i0 + hi4 * 4 + r) * 400 + (h * 32 + dt * 16 + ln) * 2) = f2bf(acc[r]);
            }
        }
        __syncthreads();
    }

    // ---- Phase 3: head projection. D[c][t] = head_w[c][j] * o[t][j] ----
    short8 bo[4][6];
    #pragma unroll
    for (int nt = 0; nt < 4; ++nt)
        #pragma unroll
        for (int kt = 0; kt < 6; ++kt)
            bo[nt][kt] = *(const short8*)(xo_lds + (nt * 16 + ln) * 400 + kt * 64 + hi4 * 16);

    #pragma unroll
    for (int mm = 0; mm < 3; ++mm) {
        const int c0 = (wid * 3 + mm) * 16;
        short8 af[6];
        #pragma unroll
        for (int kt = 0; kt < 6; ++kt)
            af[kt] = *(const short8*)(wh + (c0 + ln) * 192 + kt * 32 + hi4 * 8);
        float bias[4];
        #pragma unroll
        for (int r = 0; r < 4; ++r) bias[r] = head_b[c0 + hi4 * 4 + r];
        #pragma unroll
        for (int nt = 0; nt < 4; ++nt) {
            f32x4 acc = {0.f, 0.f, 0.f, 0.f};
            #pragma unroll
            for (int kt = 0; kt < 6; ++kt)
                acc = __builtin_amdgcn_mfma_f32_16x16x32_bf16(af[kt], bo[nt][kt], acc, 0, 0, 0);
            const int t = nt * 16 + ln;
            const int y = t >> 3, xx = t & 7;
            float* op = out + ((size_t)(b * 192) * 384 + (row0 + y)) * 384 + (col0 + xx);
            #pragma unroll
            for (int r = 0; r < 4; ++r) {
                const int c = c0 + hi4 * 4 + r;
                op[(size_t)c * 147456] = acc[r] + bias[r];
            }
        }
    }
}

extern "C" void kernel_launch(void* const* d_in, const int* in_sizes, int n_in,
                              void* d_out, int out_size, void* d_ws, size_t ws_size,
                              hipStream_t stream) {
    const float* x      = (const float*)d_in[0];
    const float* qkv_w  = (const float*)d_in[1];
    const float* qkv_b  = (const float*)d_in[2];
    const float* head_w = (const float*)d_in[3];
    const float* head_b = (const float*)d_in[4];
    float* out = (float*)d_out;

    unsigned short* wq = (unsigned short*)d_ws;
    unsigned short* wh = wq + 576 * 192;

    cvt_weights<<<576, 256, 0, stream>>>(qkv_w, head_w, wq, wh);

    hipFuncSetAttribute((const void*)wmha, hipFuncAttributeMaxDynamicSharedMemorySize, SMEM_BYTES);
    wmha<<<9216, 256, SMEM_BYTES, stream>>>(x, qkv_b, head_b, wq, wh, out);
}